// Round 2
// baseline (965.752 us; speedup 1.0000x reference)
//
#include <hip/hip_runtime.h>
#include <cstdint>

// ---------------------------------------------------------------------------
// LaSSMDecoder on MI355X — fp32 baseline, chunked (SSD) Mamba2 scan.
// Sizes fixed by the problem:
//   Q=2048 queries, N=32768 superpoints, D=256, K=8 neighbors,
//   H=8 heads, HD=64, ST=64, DIN=512, CONV=640, NPROJ=1160, HID=1024, NL=2, KC=4
// ---------------------------------------------------------------------------

// -------------------------- KNN (top-8 by squared distance) ----------------
__global__ __launch_bounds__(256) void knn_kernel(
    const float* __restrict__ qpos, const float* __restrict__ spos,
    int* __restrict__ idx_out)
{
#pragma clang fp contract(off)
  __shared__ float sd[2048];
  __shared__ int   si[2048];
  const int q = blockIdx.x, tid = threadIdx.x;
  const float qx = qpos[q*3+0], qy = qpos[q*3+1], qz = qpos[q*3+2];
  const float qq = qx*qx + qy*qy + qz*qz;
  float bd[8]; int bi[8];
#pragma unroll
  for (int j = 0; j < 8; ++j) { bd[j] = 3.4e38f; bi[j] = 0x7fffffff; }
  for (int n = tid; n < 32768; n += 256) {
    const float sx = spos[n*3+0], sy = spos[n*3+1], sz = spos[n*3+2];
    const float ss = sx*sx + sy*sy + sz*sz;
    const float dot = qx*sx + qy*sy + qz*sz;
    const float d2 = (qq + ss) - 2.0f*dot;   // same formula as reference
    if (d2 < bd[7]) {                         // within-thread idx ascending → strict <
      int pos = 7;
      while (pos > 0 && d2 < bd[pos-1]) { bd[pos]=bd[pos-1]; bi[pos]=bi[pos-1]; --pos; }
      bd[pos] = d2; bi[pos] = n;
    }
  }
#pragma unroll
  for (int j = 0; j < 8; ++j) { sd[tid*8+j] = bd[j]; si[tid*8+j] = bi[j]; }
  __syncthreads();
  // stage 1: 8 threads merge 32 thread-lists (256 entries) each, lexicographic
  if (tid < 8) {
#pragma unroll
    for (int j = 0; j < 8; ++j) { bd[j] = 3.4e38f; bi[j] = 0x7fffffff; }
    for (int e = tid*256; e < tid*256 + 256; ++e) {
      float d2 = sd[e]; int ii = si[e];
      if (d2 < bd[7] || (d2 == bd[7] && ii < bi[7])) {
        int pos = 7;
        while (pos > 0 && (d2 < bd[pos-1] || (d2 == bd[pos-1] && ii < bi[pos-1]))) {
          bd[pos]=bd[pos-1]; bi[pos]=bi[pos-1]; --pos;
        }
        bd[pos]=d2; bi[pos]=ii;
      }
    }
  }
  __syncthreads();
  if (tid < 8) {
#pragma unroll
    for (int j = 0; j < 8; ++j) { sd[tid*8+j] = bd[j]; si[tid*8+j] = bi[j]; }
  }
  __syncthreads();
  if (tid == 0) {
#pragma unroll
    for (int j = 0; j < 8; ++j) { bd[j] = 3.4e38f; bi[j] = 0x7fffffff; }
    for (int e = 0; e < 64; ++e) {
      float d2 = sd[e]; int ii = si[e];
      if (d2 < bd[7] || (d2 == bd[7] && ii < bi[7])) {
        int pos = 7;
        while (pos > 0 && (d2 < bd[pos-1] || (d2 == bd[pos-1] && ii < bi[pos-1]))) {
          bd[pos]=bd[pos-1]; bi[pos]=bi[pos-1]; --pos;
        }
        bd[pos]=d2; bi[pos]=ii;
      }
    }
#pragma unroll
    for (int j = 0; j < 8; ++j) idx_out[q*8+j] = bi[j];
  }
}

// -------------------------- inverse permutation ----------------------------
__global__ void inv_kernel(const int* __restrict__ order, int* __restrict__ inv)
{
  int i = blockIdx.x*blockDim.x + threadIdx.x;
  if (i < 4096) { int b = i >> 11, t = i & 2047; inv[(b<<11) + order[i]] = t; }
}

// -------------------------- generic tiled GEMM: Y = act(A[rowmap]@Wt^T + b) -
// A: [*, Kd] rows selected by rowmap (nullptr = identity); Wt: [Nn, Kd]
// act: 0 = none, 1 = exact gelu
__global__ __launch_bounds__(256) void gemm_kernel(
    const float* __restrict__ A, const int* __restrict__ rowmap,
    const float* __restrict__ Wt, const float* __restrict__ bias,
    float* __restrict__ Y, int M, int Nn, int Kd, int act)
{
  __shared__ float As[16][128];
  __shared__ float Ws[16][64];
  const int tid = threadIdx.x;
  const int bm = blockIdx.x, bn = blockIdx.y;
  const int tx = tid & 15, ty = tid >> 4;          // 16 x 16 thread grid
  const int ar = tid >> 1, ac = (tid & 1) << 3;    // A-tile load map (128x16)
  const int wr = tid >> 2, wc = (tid & 3) << 2;    // W-tile load map (64x16)
  int arow = bm*128 + ar;
  int asrc = rowmap ? rowmap[arow] : arow;
  const float* Arow = A + (size_t)asrc * Kd;
  int wrow = bn*64 + wr;
  const float* Wrow = (wrow < Nn) ? (Wt + (size_t)wrow * Kd) : nullptr;
  float acc[8][4];
#pragma unroll
  for (int i = 0; i < 8; ++i)
#pragma unroll
    for (int j = 0; j < 4; ++j) acc[i][j] = 0.f;
  for (int k0 = 0; k0 < Kd; k0 += 16) {
    float4 a0 = *(const float4*)(Arow + k0 + ac);
    float4 a1 = *(const float4*)(Arow + k0 + ac + 4);
    float4 w0 = Wrow ? *(const float4*)(Wrow + k0 + wc) : make_float4(0.f,0.f,0.f,0.f);
    As[ac+0][ar] = a0.x; As[ac+1][ar] = a0.y; As[ac+2][ar] = a0.z; As[ac+3][ar] = a0.w;
    As[ac+4][ar] = a1.x; As[ac+5][ar] = a1.y; As[ac+6][ar] = a1.z; As[ac+7][ar] = a1.w;
    Ws[wc+0][wr] = w0.x; Ws[wc+1][wr] = w0.y; Ws[wc+2][wr] = w0.z; Ws[wc+3][wr] = w0.w;
    __syncthreads();
#pragma unroll
    for (int k = 0; k < 16; ++k) {
      float4 aa0 = *(const float4*)&As[k][ty*8];
      float4 aa1 = *(const float4*)&As[k][ty*8+4];
      float4 bb  = *(const float4*)&Ws[k][tx*4];
      float am[8] = {aa0.x,aa0.y,aa0.z,aa0.w,aa1.x,aa1.y,aa1.z,aa1.w};
      float bv[4] = {bb.x,bb.y,bb.z,bb.w};
#pragma unroll
      for (int i = 0; i < 8; ++i)
#pragma unroll
        for (int j = 0; j < 4; ++j)
          acc[i][j] = fmaf(am[i], bv[j], acc[i][j]);
    }
    __syncthreads();
  }
#pragma unroll
  for (int i = 0; i < 8; ++i) {
    int m = bm*128 + ty*8 + i;   // all M here are multiples of 128
#pragma unroll
    for (int j = 0; j < 4; ++j) {
      int n = bn*64 + tx*4 + j;
      if (n < Nn) {
        float v = acc[i][j];
        if (bias) v += bias[n];
        if (act == 1) v = 0.5f*v*(1.f + erff(v*0.7071067811865475f));
        Y[(size_t)m*Nn + n] = v;
      }
    }
  }
}

// -------------------------- kw softmax + neighbor mixing -------------------
// W[q,d] = q[q,d] * sum_k softmax_k(q·w_k + w_b)[k] * V[q,k,d]
__global__ __launch_bounds__(256) void kwmix_kernel(
    const float* __restrict__ QP, const float* __restrict__ wk,
    const float* __restrict__ wb, const float* __restrict__ V,
    float* __restrict__ W)
{
  const int wave = threadIdx.x >> 6, lane = threadIdx.x & 63;
  const int q = blockIdx.x*4 + wave;
  float qv[4];
#pragma unroll
  for (int j = 0; j < 4; ++j) qv[j] = QP[(size_t)q*256 + lane + 64*j];
  float logit[8];
#pragma unroll
  for (int k = 0; k < 8; ++k) {
    float p = 0.f;
#pragma unroll
    for (int j = 0; j < 4; ++j) p += qv[j]*wk[k*256 + lane + 64*j];
    for (int off = 32; off; off >>= 1) p += __shfl_xor(p, off);
    logit[k] = p + wb[k];
  }
  float mx = logit[0];
#pragma unroll
  for (int k = 1; k < 8; ++k) mx = fmaxf(mx, logit[k]);
  float e[8]; float s = 0.f;
#pragma unroll
  for (int k = 0; k < 8; ++k) { e[k] = expf(logit[k]-mx); s += e[k]; }
  float inv = 1.f/s;
  float acc[4] = {0.f,0.f,0.f,0.f};
#pragma unroll
  for (int k = 0; k < 8; ++k) {
    float kwv = e[k]*inv;
#pragma unroll
    for (int j = 0; j < 4; ++j)
      acc[j] = fmaf(kwv, V[(size_t)(q*8+k)*256 + lane + 64*j], acc[j]);
  }
#pragma unroll
  for (int j = 0; j < 4; ++j)
    W[(size_t)q*256 + lane + 64*j] = qv[j]*acc[j];
}

// -------------------------- LayerNorm over D=256 (1 wave / row) ------------
__global__ __launch_bounds__(256) void ln_kernel(
    const float* __restrict__ a, const float* __restrict__ b,
    float* __restrict__ out, int rows)
{
  const int wave = threadIdx.x >> 6, lane = threadIdx.x & 63;
  const int row = blockIdx.x*4 + wave;
  if (row >= rows) return;
  float v[4];
#pragma unroll
  for (int j = 0; j < 4; ++j) {
    float x = a[(size_t)row*256 + lane + 64*j];
    if (b) x += b[(size_t)row*256 + lane + 64*j];
    v[j] = x;
  }
  float s = v[0]+v[1]+v[2]+v[3];
  for (int off = 32; off; off >>= 1) s += __shfl_xor(s, off);
  float m = s * (1.0f/256.0f);
  float t = 0.f;
#pragma unroll
  for (int j = 0; j < 4; ++j) { float d = v[j]-m; t += d*d; }
  for (int off = 32; off; off >>= 1) t += __shfl_xor(t, off);
  float r = rsqrtf(t * (1.0f/256.0f) + 1e-5f);
#pragma unroll
  for (int j = 0; j < 4; ++j)
    out[(size_t)row*256 + lane + 64*j] = (v[j]-m)*r;
}

// unsort both paths + residual + LN (in-place on X)
__global__ __launch_bounds__(256) void ln_unsort_kernel(
    const float* __restrict__ OUTL, const int* __restrict__ INV,
    float* __restrict__ X)
{
  const int wave = threadIdx.x >> 6, lane = threadIdx.x & 63;
  const int q = blockIdx.x*4 + wave;
  const int i0 = INV[q], i1 = INV[2048 + q];
  float v[4];
#pragma unroll
  for (int j = 0; j < 4; ++j) {
    int d = lane + 64*j;
    v[j] = X[(size_t)q*256 + d]
         + 0.5f*(OUTL[(size_t)i0*256 + d] + OUTL[(size_t)(2048+i1)*256 + d]);
  }
  float s = v[0]+v[1]+v[2]+v[3];
  for (int off = 32; off; off >>= 1) s += __shfl_xor(s, off);
  float m = s * (1.0f/256.0f);
  float t = 0.f;
#pragma unroll
  for (int j = 0; j < 4; ++j) { float d = v[j]-m; t += d*d; }
  for (int off = 32; off; off >>= 1) t += __shfl_xor(t, off);
  float r = rsqrtf(t * (1.0f/256.0f) + 1e-5f);
#pragma unroll
  for (int j = 0; j < 4; ++j)
    X[(size_t)q*256 + lane + 64*j] = (v[j]-m)*r;
}

// -------------------------- causal depthwise conv (KC=4) + SiLU ------------
__global__ void conv_kernel(const float* __restrict__ PROJ,
    const float* __restrict__ Wc, const float* __restrict__ bc,
    float* __restrict__ XBC)
{
  const int c = threadIdx.x;      // 640
  const int bt = blockIdx.x;      // 4096
  const int t = bt & 2047;
  float acc = bc[c];
#pragma unroll
  for (int j = 0; j < 4; ++j) {
    int d = j - 3;
    if (t + d >= 0)
      acc = fmaf(PROJ[(size_t)(bt + d)*1160 + 512 + c], Wc[c*4+j], acc);
  }
  XBC[(size_t)bt*640 + c] = acc / (1.f + expf(-acc));  // silu
}

// -------------------------- dt softplus + dA -------------------------------
// outputs transposed: Ddt/Dda layout [H][B*T] for coalesced scan reads
__global__ void dta_kernel(const float* __restrict__ PROJ,
    const float* __restrict__ dtb, const float* __restrict__ Alog,
    float* __restrict__ Ddt, float* __restrict__ Dda)
{
  const int i = blockIdx.x*256 + threadIdx.x;   // 32768 = 4096*8
  const int bt = i >> 3, hh = i & 7;
  float x = PROJ[(size_t)bt*1160 + 1152 + hh] + dtb[hh];
  float dt = (x > 20.f) ? x : log1pf(expf(x));
  float A = -expf(Alog[hh]);
  Ddt[hh*4096 + bt] = dt;
  Dda[hh*4096 + bt] = expf(dt * A);
}

// -------------------------- scan pass 1: per-chunk S_c, P_c ----------------
// grid = b(2) * h(8) * chunk(32) = 512 blocks, 64 threads (lane = d)
__global__ __launch_bounds__(64) void scan1_kernel(
    const float* __restrict__ XBC, const float* __restrict__ Ddt,
    const float* __restrict__ Dda, float* __restrict__ SCH, float* __restrict__ PC)
{
  const int blk = blockIdx.x;
  const int c = blk & 31, hh = (blk >> 5) & 7, b = blk >> 8;
  const int lane = threadIdx.x;
  const int t0 = (b << 11) + (c << 6);
  __shared__ float Bsh[64][64];
  __shared__ float Xsh[64][64];
  __shared__ float dAs[64], dts[64];
  // float4 tile staging: 16 iters, each wave covers 4 rows coalesced
#pragma unroll
  for (int it = 0; it < 16; ++it) {
    int idx = it*64 + lane;          // 0..1023
    int t = idx >> 4, c4 = (idx & 15) << 2;
    *(float4*)&Bsh[t][c4] = *(const float4*)&XBC[(size_t)(t0 + t)*640 + 512 + c4];
    *(float4*)&Xsh[t][c4] = *(const float4*)&XBC[(size_t)(t0 + t)*640 + (hh<<6) + c4];
  }
  dAs[lane] = Dda[hh*4096 + t0 + lane];
  dts[lane] = Ddt[hh*4096 + t0 + lane];
  __syncthreads();
  float h[64];
#pragma unroll
  for (int s = 0; s < 64; ++s) h[s] = 0.f;
  float p = 1.f;
  for (int t = 0; t < 64; ++t) {
    const float dA = dAs[t];
    const float u = dts[t]*Xsh[t][lane];
    p *= dA;
    const float4* B4 = (const float4*)&Bsh[t][0];
#pragma unroll
    for (int s4 = 0; s4 < 16; ++s4) {
      float4 bv = B4[s4];
      h[4*s4+0] = fmaf(h[4*s4+0], dA, bv.x*u);
      h[4*s4+1] = fmaf(h[4*s4+1], dA, bv.y*u);
      h[4*s4+2] = fmaf(h[4*s4+2], dA, bv.z*u);
      h[4*s4+3] = fmaf(h[4*s4+3], dA, bv.w*u);
    }
  }
  float* op = SCH + (size_t)blk*4096 + lane*64;
#pragma unroll
  for (int s4 = 0; s4 < 16; ++s4)
    ((float4*)op)[s4] = make_float4(h[4*s4], h[4*s4+1], h[4*s4+2], h[4*s4+3]);
  if (lane == 0) PC[blk] = p;
}

// -------------------------- sequential cross-chunk combine (in-place) ------
// After this, SCH[(bh,c)] holds h_start of chunk c.
__global__ void combine_kernel(float* __restrict__ SCH, const float* __restrict__ PC)
{
  const int tid = blockIdx.x*256 + threadIdx.x;   // 65536
  const int bh = tid >> 12, ds = tid & 4095;
  float h = 0.f;
  for (int cc = 0; cc < 32; ++cc) {
    size_t o = ((size_t)(bh*32 + cc) << 12) + ds;
    float s = SCH[o];
    SCH[o] = h;
    h = fmaf(h, PC[bh*32+cc], s);
  }
}

// -------------------------- scan pass 2: exact recurrence + y --------------
__global__ __launch_bounds__(64) void scan2_kernel(
    const float* __restrict__ XBC, const float* __restrict__ Ddt,
    const float* __restrict__ Dda, const float* __restrict__ HST,
    const float* __restrict__ Dm, float* __restrict__ Yout)
{
  const int blk = blockIdx.x;
  const int c = blk & 31, hh = (blk >> 5) & 7, b = blk >> 8;
  const int lane = threadIdx.x;
  const int t0 = (b << 11) + (c << 6);
  __shared__ float Bsh[64][64];
  __shared__ float Csh[64][64];
  __shared__ float Xsh[64][64];
  __shared__ float dAs[64], dts[64];
#pragma unroll
  for (int it = 0; it < 16; ++it) {
    int idx = it*64 + lane;
    int t = idx >> 4, c4 = (idx & 15) << 2;
    *(float4*)&Bsh[t][c4] = *(const float4*)&XBC[(size_t)(t0 + t)*640 + 512 + c4];
    *(float4*)&Csh[t][c4] = *(const float4*)&XBC[(size_t)(t0 + t)*640 + 576 + c4];
    *(float4*)&Xsh[t][c4] = *(const float4*)&XBC[(size_t)(t0 + t)*640 + (hh<<6) + c4];
  }
  dAs[lane] = Dda[hh*4096 + t0 + lane];
  dts[lane] = Ddt[hh*4096 + t0 + lane];
  const float Dh = Dm[hh];
  float h[64];
  const float4* hp = (const float4*)(HST + (size_t)blk*4096 + lane*64);
#pragma unroll
  for (int s4 = 0; s4 < 16; ++s4) {
    float4 t4 = hp[s4];
    h[4*s4+0]=t4.x; h[4*s4+1]=t4.y; h[4*s4+2]=t4.z; h[4*s4+3]=t4.w;
  }
  __syncthreads();
  for (int t = 0; t < 64; ++t) {
    const float dA = dAs[t];
    const float u = dts[t]*Xsh[t][lane];
    float y = 0.f;
    const float4* B4 = (const float4*)&Bsh[t][0];
    const float4* C4 = (const float4*)&Csh[t][0];
#pragma unroll
    for (int s4 = 0; s4 < 16; ++s4) {
      float4 bv = B4[s4];
      float4 cv = C4[s4];
      h[4*s4+0] = fmaf(h[4*s4+0], dA, bv.x*u); y = fmaf(cv.x, h[4*s4+0], y);
      h[4*s4+1] = fmaf(h[4*s4+1], dA, bv.y*u); y = fmaf(cv.y, h[4*s4+1], y);
      h[4*s4+2] = fmaf(h[4*s4+2], dA, bv.z*u); y = fmaf(cv.z, h[4*s4+2], y);
      h[4*s4+3] = fmaf(h[4*s4+3], dA, bv.w*u); y = fmaf(cv.w, h[4*s4+3], y);
    }
    Yout[(size_t)(t0 + t)*512 + (hh<<6) + lane] = y + Dh*Xsh[t][lane];
  }
}

// -------------------------- gate (silu(z)) + RMSNorm over 512 (in-place) ---
__global__ __launch_bounds__(256) void gaterms_kernel(
    float* __restrict__ Y, const float* __restrict__ PROJ,
    const float* __restrict__ rmsw)
{
  const int wave = threadIdx.x >> 6, lane = threadIdx.x & 63;
  const int row = blockIdx.x*4 + wave;   // 4096
  float v[8]; float ss = 0.f;
#pragma unroll
  for (int j = 0; j < 8; ++j) {
    float y = Y[(size_t)row*512 + lane + 64*j];
    float z = PROJ[(size_t)row*1160 + lane + 64*j];
    float g = y * (z / (1.f + expf(-z)));
    v[j] = g; ss += g*g;
  }
  for (int off = 32; off; off >>= 1) ss += __shfl_xor(ss, off);
  float r = rsqrtf(ss * (1.0f/512.0f) + 1e-5f);
#pragma unroll
  for (int j = 0; j < 8; ++j)
    Y[(size_t)row*512 + lane + 64*j] = v[j] * r * rmsw[lane + 64*j];
}

// ---------------------------------------------------------------------------
extern "C" void kernel_launch(void* const* d_in, const int* in_sizes, int n_in,
                              void* d_out, int out_size, void* d_ws, size_t ws_size,
                              hipStream_t stream)
{
  (void)in_sizes; (void)n_in; (void)out_size; (void)ws_size;
  const float* query = (const float*)d_in[0];
  const float* qpos  = (const float*)d_in[1];
  const float* feats = (const float*)d_in[2];
  const float* spos  = (const float*)d_in[3];
  const float* w_q   = (const float*)d_in[4];
  const float* w_v   = (const float*)d_in[5];
  const float* w_o   = (const float*)d_in[6];
  const float* w_k   = (const float*)d_in[7];
  const float* w_b   = (const float*)d_in[8];
  const float* Win   = (const float*)d_in[9];
  const float* Wconv = (const float*)d_in[10];
  const float* bconv = (const float*)d_in[11];
  const float* Alog  = (const float*)d_in[12];
  const float* Dm    = (const float*)d_in[13];
  const float* dtb   = (const float*)d_in[14];
  const float* rmsw  = (const float*)d_in[15];
  const float* Wout  = (const float*)d_in[16];
  const float* fw1   = (const float*)d_in[17];
  const float* fb1   = (const float*)d_in[18];
  const float* fw2   = (const float*)d_in[19];
  const float* fb2   = (const float*)d_in[20];
  const int*   order = (const int*)d_in[21];
  float* out = (float*)d_out;

  char* ws = (char*)d_ws;
  size_t off = 0;
  auto alloc = [&](size_t bytes) -> void* {
    void* p = ws + off;
    off = (off + bytes + 255) & ~(size_t)255;
    return p;
  };
  int*   IDX = (int*)alloc((size_t)2048*8*4);
  int*   INV = (int*)alloc((size_t)4096*4);
  float* PC  = (float*)alloc((size_t)512*4);
  float* Ddt = (float*)alloc((size_t)4096*8*4);
  float* Dda = (float*)alloc((size_t)4096*8*4);
  float* QP  = (float*)alloc((size_t)2048*256*4);
  float* WB  = (float*)alloc((size_t)2048*256*4);
  float* WO  = (float*)alloc((size_t)2048*256*4);
  float* X   = (float*)alloc((size_t)2048*256*4);
  float* XN  = (float*)alloc((size_t)2048*256*4);
  float* U1  = (float*)alloc((size_t)4096*1160*4);  // V (16MB) | PROJ (19MB)
  float* U2  = (float*)alloc((size_t)4096*640*4);   // XBC (10.5MB) | FFH (8.4MB)
  float* SCH = (float*)alloc((size_t)512*4096*4);   // chunk states (in-place h_start)
  float* Yb  = (float*)alloc((size_t)4096*512*4);
  float* U6  = (float*)alloc((size_t)4096*256*4);   // OUTL | FFO
  float* Vb   = U1;  float* PROJ = U1;
  float* XBC  = U2;  float* FFH  = U2;
  float* OUTL = U6;  float* FFO  = U6;

  // --- stage 1: KNN + aggregation ---
  inv_kernel<<<16, 256, 0, stream>>>(order, INV);
  knn_kernel<<<2048, 256, 0, stream>>>(qpos, spos, IDX);
  gemm_kernel<<<dim3(16,4), 256, 0, stream>>>(query, nullptr, w_q, nullptr, QP, 2048,256,256,0);
  gemm_kernel<<<dim3(128,4), 256, 0, stream>>>(feats, IDX, w_v, nullptr, Vb, 16384,256,256,0);
  kwmix_kernel<<<512, 256, 0, stream>>>(QP, w_k, w_b, Vb, WB);
  gemm_kernel<<<dim3(16,4), 256, 0, stream>>>(WB, nullptr, w_o, nullptr, WO, 2048,256,256,0);
  ln_kernel<<<512, 256, 0, stream>>>(WO, query, X, 2048);

  // --- stage 2: two Mamba2 layers ---
  for (int l = 0; l < 2; ++l) {
    ln_kernel<<<512, 256, 0, stream>>>(X, nullptr, XN, 2048);
    gemm_kernel<<<dim3(32,19), 256, 0, stream>>>(XN, order, Win + (size_t)l*1160*256,
                                                 nullptr, PROJ, 4096,1160,256,0);
    conv_kernel<<<4096, 640, 0, stream>>>(PROJ, Wconv + l*640*4, bconv + l*640, XBC);
    dta_kernel<<<128, 256, 0, stream>>>(PROJ, dtb + l*8, Alog + l*8, Ddt, Dda);
    scan1_kernel<<<512, 64, 0, stream>>>(XBC, Ddt, Dda, SCH, PC);
    combine_kernel<<<256, 256, 0, stream>>>(SCH, PC);
    scan2_kernel<<<512, 64, 0, stream>>>(XBC, Ddt, Dda, SCH, Dm + l*8, Yb);
    gaterms_kernel<<<1024, 256, 0, stream>>>(Yb, PROJ, rmsw + l*512);
    gemm_kernel<<<dim3(32,4), 256, 0, stream>>>(Yb, nullptr, Wout + (size_t)l*256*512,
                                                nullptr, OUTL, 4096,256,512,0);
    ln_unsort_kernel<<<512, 256, 0, stream>>>(OUTL, INV, X);
  }

  // --- stage 3: FFN ---
  gemm_kernel<<<dim3(16,16), 256, 0, stream>>>(X, nullptr, fw1, fb1, FFH, 2048,1024,256,1);
  gemm_kernel<<<dim3(16,4), 256, 0, stream>>>(FFH, nullptr, fw2, fb2, FFO, 2048,256,1024,0);
  ln_kernel<<<512, 256, 0, stream>>>(FFO, X, out, 2048);
}

// Round 3
// 858.311 us; speedup vs baseline: 1.1252x; 1.1252x over previous
//
#include <hip/hip_runtime.h>
#include <cstdint>

// ---------------------------------------------------------------------------
// LaSSMDecoder on MI355X — fp32 baseline, chunked (SSD) Mamba2 scan.
// Round 3: KNN top-8 rewritten register-resident + branchless (was scratch-
// backed insertion sort @ VGPR=20 → 314 µs, 1/3 of total).
// ---------------------------------------------------------------------------

__device__ __forceinline__ bool knn_less(float d, int i, float dref, int iref) {
  return d < dref || (d == dref && i < iref);
}

// -------------------------- KNN (top-8 by squared distance) ----------------
__global__ __launch_bounds__(256) void knn_kernel(
    const float* __restrict__ qpos, const float* __restrict__ spos,
    int* __restrict__ idx_out)
{
#pragma clang fp contract(off)
  __shared__ float sd[2048];   // [8][256] transposed: sd[j*256+t]
  __shared__ int   si[2048];
  const int q = blockIdx.x, tid = threadIdx.x;
  const float qx = qpos[q*3+0], qy = qpos[q*3+1], qz = qpos[q*3+2];
  const float qq = qx*qx + qy*qy + qz*qz;
  float bd[8]; int bi[8];
#pragma unroll
  for (int j = 0; j < 8; ++j) { bd[j] = 3.4e38f; bi[j] = 0x7fffffff; }
  // phase 0: per-thread top-8 over its 128-point stream (indices ascending →
  // strict < keeps the earlier index on ties, matching top_k stability)
  for (int n = tid; n < 32768; n += 256) {
    const float sx = spos[n*3+0], sy = spos[n*3+1], sz = spos[n*3+2];
    const float ss = sx*sx + sy*sy + sz*sz;
    const float dot = qx*sx + qy*sy + qz*sz;
    const float d2 = (qq + ss) - 2.0f*dot;   // reference's exact formula
    if (d2 < bd[7]) {
      // branchless one-slot insert, all indices compile-time → registers
#pragma unroll
      for (int j = 7; j >= 1; --j) {
        const bool sh = d2 < bd[j-1];   // shift down
        const bool at = d2 < bd[j];     // lands here (exactly one slot has !sh&&at)
        bd[j] = sh ? bd[j-1] : (at ? d2 : bd[j]);
        bi[j] = sh ? bi[j-1] : (at ? n  : bi[j]);
      }
      const bool at0 = d2 < bd[0];
      bd[0] = at0 ? d2 : bd[0];
      bi[0] = at0 ? n  : bi[0];
    }
  }
  // stage to LDS, transposed (consecutive tid → consecutive banks)
#pragma unroll
  for (int j = 0; j < 8; ++j) { sd[j*256+tid] = bd[j]; si[j*256+tid] = bi[j]; }
  __syncthreads();
  // phase 1: 8 threads, each merges 32 source threads' sorted lists
  if (tid < 8) {
#pragma unroll
    for (int j = 0; j < 8; ++j) { bd[j] = 3.4e38f; bi[j] = 0x7fffffff; }
    for (int s = tid*32; s < tid*32 + 32; ++s) {
#pragma unroll
      for (int j = 0; j < 8; ++j) {
        const float d2 = sd[j*256 + s];
        const int   ii = si[j*256 + s];
        if (!knn_less(d2, ii, bd[7], bi[7])) break;  // source sorted → done
#pragma unroll
        for (int k = 7; k >= 1; --k) {
          const bool sh = knn_less(d2, ii, bd[k-1], bi[k-1]);
          const bool at = knn_less(d2, ii, bd[k],   bi[k]);
          bd[k] = sh ? bd[k-1] : (at ? d2 : bd[k]);
          bi[k] = sh ? bi[k-1] : (at ? ii : bi[k]);
        }
        const bool at0 = knn_less(d2, ii, bd[0], bi[0]);
        bd[0] = at0 ? d2 : bd[0];
        bi[0] = at0 ? ii : bi[0];
      }
    }
  }
  __syncthreads();   // all phase-1 reads complete before overwrite
  if (tid < 8) {
#pragma unroll
    for (int j = 0; j < 8; ++j) { sd[j*256+tid] = bd[j]; si[j*256+tid] = bi[j]; }
  }
  __syncthreads();
  // phase 2: thread 0 merges the 8 surviving lists
  if (tid == 0) {
#pragma unroll
    for (int j = 0; j < 8; ++j) { bd[j] = 3.4e38f; bi[j] = 0x7fffffff; }
    for (int s = 0; s < 8; ++s) {
#pragma unroll
      for (int j = 0; j < 8; ++j) {
        const float d2 = sd[j*256 + s];
        const int   ii = si[j*256 + s];
        if (!knn_less(d2, ii, bd[7], bi[7])) break;
#pragma unroll
        for (int k = 7; k >= 1; --k) {
          const bool sh = knn_less(d2, ii, bd[k-1], bi[k-1]);
          const bool at = knn_less(d2, ii, bd[k],   bi[k]);
          bd[k] = sh ? bd[k-1] : (at ? d2 : bd[k]);
          bi[k] = sh ? bi[k-1] : (at ? ii : bi[k]);
        }
        const bool at0 = knn_less(d2, ii, bd[0], bi[0]);
        bd[0] = at0 ? d2 : bd[0];
        bi[0] = at0 ? ii : bi[0];
      }
    }
#pragma unroll
    for (int j = 0; j < 8; ++j) idx_out[q*8+j] = bi[j];
  }
}

// -------------------------- inverse permutation ----------------------------
__global__ void inv_kernel(const int* __restrict__ order, int* __restrict__ inv)
{
  int i = blockIdx.x*blockDim.x + threadIdx.x;
  if (i < 4096) { int b = i >> 11, t = i & 2047; inv[(b<<11) + order[i]] = t; }
}

// -------------------------- generic tiled GEMM: Y = act(A[rowmap]@Wt^T + b) -
// A: [*, Kd] rows selected by rowmap (nullptr = identity); Wt: [Nn, Kd]
// act: 0 = none, 1 = exact gelu
__global__ __launch_bounds__(256) void gemm_kernel(
    const float* __restrict__ A, const int* __restrict__ rowmap,
    const float* __restrict__ Wt, const float* __restrict__ bias,
    float* __restrict__ Y, int M, int Nn, int Kd, int act)
{
  __shared__ float As[16][128];
  __shared__ float Ws[16][64];
  const int tid = threadIdx.x;
  const int bm = blockIdx.x, bn = blockIdx.y;
  const int tx = tid & 15, ty = tid >> 4;          // 16 x 16 thread grid
  const int ar = tid >> 1, ac = (tid & 1) << 3;    // A-tile load map (128x16)
  const int wr = tid >> 2, wc = (tid & 3) << 2;    // W-tile load map (64x16)
  int arow = bm*128 + ar;
  int asrc = rowmap ? rowmap[arow] : arow;
  const float* Arow = A + (size_t)asrc * Kd;
  int wrow = bn*64 + wr;
  const float* Wrow = (wrow < Nn) ? (Wt + (size_t)wrow * Kd) : nullptr;
  float acc[8][4];
#pragma unroll
  for (int i = 0; i < 8; ++i)
#pragma unroll
    for (int j = 0; j < 4; ++j) acc[i][j] = 0.f;
  for (int k0 = 0; k0 < Kd; k0 += 16) {
    float4 a0 = *(const float4*)(Arow + k0 + ac);
    float4 a1 = *(const float4*)(Arow + k0 + ac + 4);
    float4 w0 = Wrow ? *(const float4*)(Wrow + k0 + wc) : make_float4(0.f,0.f,0.f,0.f);
    As[ac+0][ar] = a0.x; As[ac+1][ar] = a0.y; As[ac+2][ar] = a0.z; As[ac+3][ar] = a0.w;
    As[ac+4][ar] = a1.x; As[ac+5][ar] = a1.y; As[ac+6][ar] = a1.z; As[ac+7][ar] = a1.w;
    Ws[wc+0][wr] = w0.x; Ws[wc+1][wr] = w0.y; Ws[wc+2][wr] = w0.z; Ws[wc+3][wr] = w0.w;
    __syncthreads();
#pragma unroll
    for (int k = 0; k < 16; ++k) {
      float4 aa0 = *(const float4*)&As[k][ty*8];
      float4 aa1 = *(const float4*)&As[k][ty*8+4];
      float4 bb  = *(const float4*)&Ws[k][tx*4];
      float am[8] = {aa0.x,aa0.y,aa0.z,aa0.w,aa1.x,aa1.y,aa1.z,aa1.w};
      float bv[4] = {bb.x,bb.y,bb.z,bb.w};
#pragma unroll
      for (int i = 0; i < 8; ++i)
#pragma unroll
        for (int j = 0; j < 4; ++j)
          acc[i][j] = fmaf(am[i], bv[j], acc[i][j]);
    }
    __syncthreads();
  }
#pragma unroll
  for (int i = 0; i < 8; ++i) {
    int m = bm*128 + ty*8 + i;   // all M here are multiples of 128
#pragma unroll
    for (int j = 0; j < 4; ++j) {
      int n = bn*64 + tx*4 + j;
      if (n < Nn) {
        float v = acc[i][j];
        if (bias) v += bias[n];
        if (act == 1) v = 0.5f*v*(1.f + erff(v*0.7071067811865475f));
        Y[(size_t)m*Nn + n] = v;
      }
    }
  }
}

// -------------------------- kw softmax + neighbor mixing -------------------
// W[q,d] = q[q,d] * sum_k softmax_k(q·w_k + w_b)[k] * V[q,k,d]
__global__ __launch_bounds__(256) void kwmix_kernel(
    const float* __restrict__ QP, const float* __restrict__ wk,
    const float* __restrict__ wb, const float* __restrict__ V,
    float* __restrict__ W)
{
  const int wave = threadIdx.x >> 6, lane = threadIdx.x & 63;
  const int q = blockIdx.x*4 + wave;
  float qv[4];
#pragma unroll
  for (int j = 0; j < 4; ++j) qv[j] = QP[(size_t)q*256 + lane + 64*j];
  float logit[8];
#pragma unroll
  for (int k = 0; k < 8; ++k) {
    float p = 0.f;
#pragma unroll
    for (int j = 0; j < 4; ++j) p += qv[j]*wk[k*256 + lane + 64*j];
    for (int off = 32; off; off >>= 1) p += __shfl_xor(p, off);
    logit[k] = p + wb[k];
  }
  float mx = logit[0];
#pragma unroll
  for (int k = 1; k < 8; ++k) mx = fmaxf(mx, logit[k]);
  float e[8]; float s = 0.f;
#pragma unroll
  for (int k = 0; k < 8; ++k) { e[k] = expf(logit[k]-mx); s += e[k]; }
  float inv = 1.f/s;
  float acc[4] = {0.f,0.f,0.f,0.f};
#pragma unroll
  for (int k = 0; k < 8; ++k) {
    float kwv = e[k]*inv;
#pragma unroll
    for (int j = 0; j < 4; ++j)
      acc[j] = fmaf(kwv, V[(size_t)(q*8+k)*256 + lane + 64*j], acc[j]);
  }
#pragma unroll
  for (int j = 0; j < 4; ++j)
    W[(size_t)q*256 + lane + 64*j] = qv[j]*acc[j];
}

// -------------------------- LayerNorm over D=256 (1 wave / row) ------------
__global__ __launch_bounds__(256) void ln_kernel(
    const float* __restrict__ a, const float* __restrict__ b,
    float* __restrict__ out, int rows)
{
  const int wave = threadIdx.x >> 6, lane = threadIdx.x & 63;
  const int row = blockIdx.x*4 + wave;
  if (row >= rows) return;
  float v[4];
#pragma unroll
  for (int j = 0; j < 4; ++j) {
    float x = a[(size_t)row*256 + lane + 64*j];
    if (b) x += b[(size_t)row*256 + lane + 64*j];
    v[j] = x;
  }
  float s = v[0]+v[1]+v[2]+v[3];
  for (int off = 32; off; off >>= 1) s += __shfl_xor(s, off);
  float m = s * (1.0f/256.0f);
  float t = 0.f;
#pragma unroll
  for (int j = 0; j < 4; ++j) { float d = v[j]-m; t += d*d; }
  for (int off = 32; off; off >>= 1) t += __shfl_xor(t, off);
  float r = rsqrtf(t * (1.0f/256.0f) + 1e-5f);
#pragma unroll
  for (int j = 0; j < 4; ++j)
    out[(size_t)row*256 + lane + 64*j] = (v[j]-m)*r;
}

// unsort both paths + residual + LN (in-place on X)
__global__ __launch_bounds__(256) void ln_unsort_kernel(
    const float* __restrict__ OUTL, const int* __restrict__ INV,
    float* __restrict__ X)
{
  const int wave = threadIdx.x >> 6, lane = threadIdx.x & 63;
  const int q = blockIdx.x*4 + wave;
  const int i0 = INV[q], i1 = INV[2048 + q];
  float v[4];
#pragma unroll
  for (int j = 0; j < 4; ++j) {
    int d = lane + 64*j;
    v[j] = X[(size_t)q*256 + d]
         + 0.5f*(OUTL[(size_t)i0*256 + d] + OUTL[(size_t)(2048+i1)*256 + d]);
  }
  float s = v[0]+v[1]+v[2]+v[3];
  for (int off = 32; off; off >>= 1) s += __shfl_xor(s, off);
  float m = s * (1.0f/256.0f);
  float t = 0.f;
#pragma unroll
  for (int j = 0; j < 4; ++j) { float d = v[j]-m; t += d*d; }
  for (int off = 32; off; off >>= 1) t += __shfl_xor(t, off);
  float r = rsqrtf(t * (1.0f/256.0f) + 1e-5f);
#pragma unroll
  for (int j = 0; j < 4; ++j)
    X[(size_t)q*256 + lane + 64*j] = (v[j]-m)*r;
}

// -------------------------- causal depthwise conv (KC=4) + SiLU ------------
__global__ void conv_kernel(const float* __restrict__ PROJ,
    const float* __restrict__ Wc, const float* __restrict__ bc,
    float* __restrict__ XBC)
{
  const int c = threadIdx.x;      // 640
  const int bt = blockIdx.x;      // 4096
  const int t = bt & 2047;
  float acc = bc[c];
#pragma unroll
  for (int j = 0; j < 4; ++j) {
    int d = j - 3;
    if (t + d >= 0)
      acc = fmaf(PROJ[(size_t)(bt + d)*1160 + 512 + c], Wc[c*4+j], acc);
  }
  XBC[(size_t)bt*640 + c] = acc / (1.f + expf(-acc));  // silu
}

// -------------------------- dt softplus + dA -------------------------------
// outputs transposed: Ddt/Dda layout [H][B*T] for coalesced scan reads
__global__ void dta_kernel(const float* __restrict__ PROJ,
    const float* __restrict__ dtb, const float* __restrict__ Alog,
    float* __restrict__ Ddt, float* __restrict__ Dda)
{
  const int i = blockIdx.x*256 + threadIdx.x;   // 32768 = 4096*8
  const int bt = i >> 3, hh = i & 7;
  float x = PROJ[(size_t)bt*1160 + 1152 + hh] + dtb[hh];
  float dt = (x > 20.f) ? x : log1pf(expf(x));
  float A = -expf(Alog[hh]);
  Ddt[hh*4096 + bt] = dt;
  Dda[hh*4096 + bt] = expf(dt * A);
}

// -------------------------- scan pass 1: per-chunk S_c, P_c ----------------
// grid = b(2) * h(8) * chunk(32) = 512 blocks, 64 threads (lane = d)
__global__ __launch_bounds__(64) void scan1_kernel(
    const float* __restrict__ XBC, const float* __restrict__ Ddt,
    const float* __restrict__ Dda, float* __restrict__ SCH, float* __restrict__ PC)
{
  const int blk = blockIdx.x;
  const int c = blk & 31, hh = (blk >> 5) & 7, b = blk >> 8;
  const int lane = threadIdx.x;
  const int t0 = (b << 11) + (c << 6);
  __shared__ float Bsh[64][64];
  __shared__ float Xsh[64][64];
  __shared__ float dAs[64], dts[64];
  // float4 tile staging: 16 iters, each wave covers 4 rows coalesced
#pragma unroll
  for (int it = 0; it < 16; ++it) {
    int idx = it*64 + lane;          // 0..1023
    int t = idx >> 4, c4 = (idx & 15) << 2;
    *(float4*)&Bsh[t][c4] = *(const float4*)&XBC[(size_t)(t0 + t)*640 + 512 + c4];
    *(float4*)&Xsh[t][c4] = *(const float4*)&XBC[(size_t)(t0 + t)*640 + (hh<<6) + c4];
  }
  dAs[lane] = Dda[hh*4096 + t0 + lane];
  dts[lane] = Ddt[hh*4096 + t0 + lane];
  __syncthreads();
  float h[64];
#pragma unroll
  for (int s = 0; s < 64; ++s) h[s] = 0.f;
  float p = 1.f;
  for (int t = 0; t < 64; ++t) {
    const float dA = dAs[t];
    const float u = dts[t]*Xsh[t][lane];
    p *= dA;
    const float4* B4 = (const float4*)&Bsh[t][0];
#pragma unroll
    for (int s4 = 0; s4 < 16; ++s4) {
      float4 bv = B4[s4];
      h[4*s4+0] = fmaf(h[4*s4+0], dA, bv.x*u);
      h[4*s4+1] = fmaf(h[4*s4+1], dA, bv.y*u);
      h[4*s4+2] = fmaf(h[4*s4+2], dA, bv.z*u);
      h[4*s4+3] = fmaf(h[4*s4+3], dA, bv.w*u);
    }
  }
  float* op = SCH + (size_t)blk*4096 + lane*64;
#pragma unroll
  for (int s4 = 0; s4 < 16; ++s4)
    ((float4*)op)[s4] = make_float4(h[4*s4], h[4*s4+1], h[4*s4+2], h[4*s4+3]);
  if (lane == 0) PC[blk] = p;
}

// -------------------------- sequential cross-chunk combine (in-place) ------
// After this, SCH[(bh,c)] holds h_start of chunk c.
__global__ void combine_kernel(float* __restrict__ SCH, const float* __restrict__ PC)
{
  const int tid = blockIdx.x*256 + threadIdx.x;   // 65536
  const int bh = tid >> 12, ds = tid & 4095;
  float h = 0.f;
  for (int cc = 0; cc < 32; ++cc) {
    size_t o = ((size_t)(bh*32 + cc) << 12) + ds;
    float s = SCH[o];
    SCH[o] = h;
    h = fmaf(h, PC[bh*32+cc], s);
  }
}

// -------------------------- scan pass 2: exact recurrence + y --------------
__global__ __launch_bounds__(64) void scan2_kernel(
    const float* __restrict__ XBC, const float* __restrict__ Ddt,
    const float* __restrict__ Dda, const float* __restrict__ HST,
    const float* __restrict__ Dm, float* __restrict__ Yout)
{
  const int blk = blockIdx.x;
  const int c = blk & 31, hh = (blk >> 5) & 7, b = blk >> 8;
  const int lane = threadIdx.x;
  const int t0 = (b << 11) + (c << 6);
  __shared__ float Bsh[64][64];
  __shared__ float Csh[64][64];
  __shared__ float Xsh[64][64];
  __shared__ float dAs[64], dts[64];
#pragma unroll
  for (int it = 0; it < 16; ++it) {
    int idx = it*64 + lane;
    int t = idx >> 4, c4 = (idx & 15) << 2;
    *(float4*)&Bsh[t][c4] = *(const float4*)&XBC[(size_t)(t0 + t)*640 + 512 + c4];
    *(float4*)&Csh[t][c4] = *(const float4*)&XBC[(size_t)(t0 + t)*640 + 576 + c4];
    *(float4*)&Xsh[t][c4] = *(const float4*)&XBC[(size_t)(t0 + t)*640 + (hh<<6) + c4];
  }
  dAs[lane] = Dda[hh*4096 + t0 + lane];
  dts[lane] = Ddt[hh*4096 + t0 + lane];
  const float Dh = Dm[hh];
  float h[64];
  const float4* hp = (const float4*)(HST + (size_t)blk*4096 + lane*64);
#pragma unroll
  for (int s4 = 0; s4 < 16; ++s4) {
    float4 t4 = hp[s4];
    h[4*s4+0]=t4.x; h[4*s4+1]=t4.y; h[4*s4+2]=t4.z; h[4*s4+3]=t4.w;
  }
  __syncthreads();
  for (int t = 0; t < 64; ++t) {
    const float dA = dAs[t];
    const float u = dts[t]*Xsh[t][lane];
    float y = 0.f;
    const float4* B4 = (const float4*)&Bsh[t][0];
    const float4* C4 = (const float4*)&Csh[t][0];
#pragma unroll
    for (int s4 = 0; s4 < 16; ++s4) {
      float4 bv = B4[s4];
      float4 cv = C4[s4];
      h[4*s4+0] = fmaf(h[4*s4+0], dA, bv.x*u); y = fmaf(cv.x, h[4*s4+0], y);
      h[4*s4+1] = fmaf(h[4*s4+1], dA, bv.y*u); y = fmaf(cv.y, h[4*s4+1], y);
      h[4*s4+2] = fmaf(h[4*s4+2], dA, bv.z*u); y = fmaf(cv.z, h[4*s4+2], y);
      h[4*s4+3] = fmaf(h[4*s4+3], dA, bv.w*u); y = fmaf(cv.w, h[4*s4+3], y);
    }
    Yout[(size_t)(t0 + t)*512 + (hh<<6) + lane] = y + Dh*Xsh[t][lane];
  }
}

// -------------------------- gate (silu(z)) + RMSNorm over 512 (in-place) ---
__global__ __launch_bounds__(256) void gaterms_kernel(
    float* __restrict__ Y, const float* __restrict__ PROJ,
    const float* __restrict__ rmsw)
{
  const int wave = threadIdx.x >> 6, lane = threadIdx.x & 63;
  const int row = blockIdx.x*4 + wave;   // 4096
  float v[8]; float ss = 0.f;
#pragma unroll
  for (int j = 0; j < 8; ++j) {
    float y = Y[(size_t)row*512 + lane + 64*j];
    float z = PROJ[(size_t)row*1160 + lane + 64*j];
    float g = y * (z / (1.f + expf(-z)));
    v[j] = g; ss += g*g;
  }
  for (int off = 32; off; off >>= 1) ss += __shfl_xor(ss, off);
  float r = rsqrtf(ss * (1.0f/512.0f) + 1e-5f);
#pragma unroll
  for (int j = 0; j < 8; ++j)
    Y[(size_t)row*512 + lane + 64*j] = v[j] * r * rmsw[lane + 64*j];
}

// ---------------------------------------------------------------------------
extern "C" void kernel_launch(void* const* d_in, const int* in_sizes, int n_in,
                              void* d_out, int out_size, void* d_ws, size_t ws_size,
                              hipStream_t stream)
{
  (void)in_sizes; (void)n_in; (void)out_size; (void)ws_size;
  const float* query = (const float*)d_in[0];
  const float* qpos  = (const float*)d_in[1];
  const float* feats = (const float*)d_in[2];
  const float* spos  = (const float*)d_in[3];
  const float* w_q   = (const float*)d_in[4];
  const float* w_v   = (const float*)d_in[5];
  const float* w_o   = (const float*)d_in[6];
  const float* w_k   = (const float*)d_in[7];
  const float* w_b   = (const float*)d_in[8];
  const float* Win   = (const float*)d_in[9];
  const float* Wconv = (const float*)d_in[10];
  const float* bconv = (const float*)d_in[11];
  const float* Alog  = (const float*)d_in[12];
  const float* Dm    = (const float*)d_in[13];
  const float* dtb   = (const float*)d_in[14];
  const float* rmsw  = (const float*)d_in[15];
  const float* Wout  = (const float*)d_in[16];
  const float* fw1   = (const float*)d_in[17];
  const float* fb1   = (const float*)d_in[18];
  const float* fw2   = (const float*)d_in[19];
  const float* fb2   = (const float*)d_in[20];
  const int*   order = (const int*)d_in[21];
  float* out = (float*)d_out;

  char* ws = (char*)d_ws;
  size_t off = 0;
  auto alloc = [&](size_t bytes) -> void* {
    void* p = ws + off;
    off = (off + bytes + 255) & ~(size_t)255;
    return p;
  };
  int*   IDX = (int*)alloc((size_t)2048*8*4);
  int*   INV = (int*)alloc((size_t)4096*4);
  float* PC  = (float*)alloc((size_t)512*4);
  float* Ddt = (float*)alloc((size_t)4096*8*4);
  float* Dda = (float*)alloc((size_t)4096*8*4);
  float* QP  = (float*)alloc((size_t)2048*256*4);
  float* WB  = (float*)alloc((size_t)2048*256*4);
  float* WO  = (float*)alloc((size_t)2048*256*4);
  float* X   = (float*)alloc((size_t)2048*256*4);
  float* XN  = (float*)alloc((size_t)2048*256*4);
  float* U1  = (float*)alloc((size_t)4096*1160*4);  // V (16MB) | PROJ (19MB)
  float* U2  = (float*)alloc((size_t)4096*640*4);   // XBC (10.5MB) | FFH (8.4MB)
  float* SCH = (float*)alloc((size_t)512*4096*4);   // chunk states (in-place h_start)
  float* Yb  = (float*)alloc((size_t)4096*512*4);
  float* U6  = (float*)alloc((size_t)4096*256*4);   // OUTL | FFO
  float* Vb   = U1;  float* PROJ = U1;
  float* XBC  = U2;  float* FFH  = U2;
  float* OUTL = U6;  float* FFO  = U6;

  // --- stage 1: KNN + aggregation ---
  inv_kernel<<<16, 256, 0, stream>>>(order, INV);
  knn_kernel<<<2048, 256, 0, stream>>>(qpos, spos, IDX);
  gemm_kernel<<<dim3(16,4), 256, 0, stream>>>(query, nullptr, w_q, nullptr, QP, 2048,256,256,0);
  gemm_kernel<<<dim3(128,4), 256, 0, stream>>>(feats, IDX, w_v, nullptr, Vb, 16384,256,256,0);
  kwmix_kernel<<<512, 256, 0, stream>>>(QP, w_k, w_b, Vb, WB);
  gemm_kernel<<<dim3(16,4), 256, 0, stream>>>(WB, nullptr, w_o, nullptr, WO, 2048,256,256,0);
  ln_kernel<<<512, 256, 0, stream>>>(WO, query, X, 2048);

  // --- stage 2: two Mamba2 layers ---
  for (int l = 0; l < 2; ++l) {
    ln_kernel<<<512, 256, 0, stream>>>(X, nullptr, XN, 2048);
    gemm_kernel<<<dim3(32,19), 256, 0, stream>>>(XN, order, Win + (size_t)l*1160*256,
                                                 nullptr, PROJ, 4096,1160,256,0);
    conv_kernel<<<4096, 640, 0, stream>>>(PROJ, Wconv + l*640*4, bconv + l*640, XBC);
    dta_kernel<<<128, 256, 0, stream>>>(PROJ, dtb + l*8, Alog + l*8, Ddt, Dda);
    scan1_kernel<<<512, 64, 0, stream>>>(XBC, Ddt, Dda, SCH, PC);
    combine_kernel<<<256, 256, 0, stream>>>(SCH, PC);
    scan2_kernel<<<512, 64, 0, stream>>>(XBC, Ddt, Dda, SCH, Dm + l*8, Yb);
    gaterms_kernel<<<1024, 256, 0, stream>>>(Yb, PROJ, rmsw + l*512);
    gemm_kernel<<<dim3(32,4), 256, 0, stream>>>(Yb, nullptr, Wout + (size_t)l*256*512,
                                                nullptr, OUTL, 4096,256,512,0);
    ln_unsort_kernel<<<512, 256, 0, stream>>>(OUTL, INV, X);
  }

  // --- stage 3: FFN ---
  gemm_kernel<<<dim3(16,16), 256, 0, stream>>>(X, nullptr, fw1, fb1, FFH, 2048,1024,256,1);
  gemm_kernel<<<dim3(16,4), 256, 0, stream>>>(FFH, nullptr, fw2, fb2, FFO, 2048,256,1024,0);
  ln_kernel<<<512, 256, 0, stream>>>(FFO, X, out, 2048);
}

// Round 4
// 819.796 us; speedup vs baseline: 1.1780x; 1.0470x over previous
//
#include <hip/hip_runtime.h>
#include <cstdint>

// ---------------------------------------------------------------------------
// LaSSMDecoder on MI355X — fp32 baseline, chunked (SSD) Mamba2 scan.
// Round 4: KNN top-8 state as 16 NAMED scalars (compiler kept arrays in
// scratch even with static indices — VGPR_Count was 20 both rounds).
// ---------------------------------------------------------------------------

__device__ __forceinline__ bool knn_less(float d, int i, float dref, int iref) {
  return d < dref || (d == dref && i < iref);
}

// Branchless one-slot insert into sorted 8-slot list held in named registers.
// Caller guarantees the candidate beats slot 7 under LESS.
#define KNN_INS(dv, iv, LESSD, LESSI)                                          \
  do {                                                                         \
    const float _d = (dv); const int _i = (iv);                                \
    const bool a0 = LESSD(_d, _i, bd0, bi0);                                   \
    const bool a1 = LESSD(_d, _i, bd1, bi1);                                   \
    const bool a2 = LESSD(_d, _i, bd2, bi2);                                   \
    const bool a3 = LESSD(_d, _i, bd3, bi3);                                   \
    const bool a4 = LESSD(_d, _i, bd4, bi4);                                   \
    const bool a5 = LESSD(_d, _i, bd5, bi5);                                   \
    const bool a6 = LESSD(_d, _i, bd6, bi6);                                   \
    bd7 = a6 ? bd6 : _d;            bi7 = a6 ? bi6 : _i;                       \
    bd6 = a5 ? bd5 : (a6 ? _d : bd6); bi6 = a5 ? bi5 : (a6 ? _i : bi6);        \
    bd5 = a4 ? bd4 : (a5 ? _d : bd5); bi5 = a4 ? bi4 : (a5 ? _i : bi5);        \
    bd4 = a3 ? bd3 : (a4 ? _d : bd4); bi4 = a3 ? bi3 : (a4 ? _i : bi4);        \
    bd3 = a2 ? bd2 : (a3 ? _d : bd3); bi3 = a2 ? bi2 : (a3 ? _i : bi3);        \
    bd2 = a1 ? bd1 : (a2 ? _d : bd2); bi2 = a1 ? bi1 : (a2 ? _i : bi2);        \
    bd1 = a0 ? bd0 : (a1 ? _d : bd1); bi1 = a0 ? bi0 : (a1 ? _i : bi1);        \
    bd0 = a0 ? _d : bd0;            bi0 = a0 ? _i : bi0;                       \
  } while (0)

#define LESS_PLAIN(d, i, dr, ir) ((d) < (dr))
#define LESS_LEX(d, i, dr, ir)   knn_less((d), (i), (dr), (ir))

#define KNN_RESET()                                                            \
  do {                                                                         \
    bd0=bd1=bd2=bd3=bd4=bd5=bd6=bd7 = 3.4e38f;                                 \
    bi0=bi1=bi2=bi3=bi4=bi5=bi6=bi7 = 0x7fffffff;                              \
  } while (0)

// -------------------------- KNN (top-8 by squared distance) ----------------
__global__ __launch_bounds__(256) void knn_kernel(
    const float* __restrict__ qpos, const float* __restrict__ spos,
    int* __restrict__ idx_out)
{
#pragma clang fp contract(off)
  __shared__ float sd[2048];   // [8][256] transposed: sd[j*256+t]
  __shared__ int   si[2048];
  const int q = blockIdx.x, tid = threadIdx.x;
  const float qx = qpos[q*3+0], qy = qpos[q*3+1], qz = qpos[q*3+2];
  const float qq = qx*qx + qy*qy + qz*qz;
  float bd0,bd1,bd2,bd3,bd4,bd5,bd6,bd7;
  int   bi0,bi1,bi2,bi3,bi4,bi5,bi6,bi7;
  KNN_RESET();
  // phase 0: per-thread top-8 over its 128-point stream (indices ascending →
  // strict < keeps the earlier index on ties, matching top_k stability)
  for (int n = tid; n < 32768; n += 256) {
    const float sx = spos[n*3+0], sy = spos[n*3+1], sz = spos[n*3+2];
    const float ss = sx*sx + sy*sy + sz*sz;
    const float dot = qx*sx + qy*sy + qz*sz;
    const float d2 = (qq + ss) - 2.0f*dot;   // reference's exact formula
    if (d2 < bd7) KNN_INS(d2, n, LESS_PLAIN, );
  }
  // stage to LDS, transposed (consecutive tid → consecutive banks)
  sd[0*256+tid]=bd0; sd[1*256+tid]=bd1; sd[2*256+tid]=bd2; sd[3*256+tid]=bd3;
  sd[4*256+tid]=bd4; sd[5*256+tid]=bd5; sd[6*256+tid]=bd6; sd[7*256+tid]=bd7;
  si[0*256+tid]=bi0; si[1*256+tid]=bi1; si[2*256+tid]=bi2; si[3*256+tid]=bi3;
  si[4*256+tid]=bi4; si[5*256+tid]=bi5; si[6*256+tid]=bi6; si[7*256+tid]=bi7;
  __syncthreads();
  // phase 1: 8 threads, each merges 32 source threads' sorted lists
  if (tid < 8) {
    KNN_RESET();
    for (int s = tid*32; s < tid*32 + 32; ++s) {
#pragma unroll
      for (int j = 0; j < 8; ++j) {
        const float d2 = sd[j*256 + s];
        const int   ii = si[j*256 + s];
        if (!knn_less(d2, ii, bd7, bi7)) break;  // source sorted → done
        KNN_INS(d2, ii, LESS_LEX, );
      }
    }
  }
  __syncthreads();   // all phase-1 reads complete before overwrite
  if (tid < 8) {
    sd[0*256+tid]=bd0; sd[1*256+tid]=bd1; sd[2*256+tid]=bd2; sd[3*256+tid]=bd3;
    sd[4*256+tid]=bd4; sd[5*256+tid]=bd5; sd[6*256+tid]=bd6; sd[7*256+tid]=bd7;
    si[0*256+tid]=bi0; si[1*256+tid]=bi1; si[2*256+tid]=bi2; si[3*256+tid]=bi3;
    si[4*256+tid]=bi4; si[5*256+tid]=bi5; si[6*256+tid]=bi6; si[7*256+tid]=bi7;
  }
  __syncthreads();
  // phase 2: thread 0 merges the 8 surviving lists
  if (tid == 0) {
    KNN_RESET();
    for (int s = 0; s < 8; ++s) {
#pragma unroll
      for (int j = 0; j < 8; ++j) {
        const float d2 = sd[j*256 + s];
        const int   ii = si[j*256 + s];
        if (!knn_less(d2, ii, bd7, bi7)) break;
        KNN_INS(d2, ii, LESS_LEX, );
      }
    }
    idx_out[q*8+0]=bi0; idx_out[q*8+1]=bi1; idx_out[q*8+2]=bi2; idx_out[q*8+3]=bi3;
    idx_out[q*8+4]=bi4; idx_out[q*8+5]=bi5; idx_out[q*8+6]=bi6; idx_out[q*8+7]=bi7;
  }
}

// -------------------------- inverse permutation ----------------------------
__global__ void inv_kernel(const int* __restrict__ order, int* __restrict__ inv)
{
  int i = blockIdx.x*blockDim.x + threadIdx.x;
  if (i < 4096) { int b = i >> 11, t = i & 2047; inv[(b<<11) + order[i]] = t; }
}

// -------------------------- generic tiled GEMM: Y = act(A[rowmap]@Wt^T + b) -
// A: [*, Kd] rows selected by rowmap (nullptr = identity); Wt: [Nn, Kd]
// act: 0 = none, 1 = exact gelu
__global__ __launch_bounds__(256) void gemm_kernel(
    const float* __restrict__ A, const int* __restrict__ rowmap,
    const float* __restrict__ Wt, const float* __restrict__ bias,
    float* __restrict__ Y, int M, int Nn, int Kd, int act)
{
  __shared__ float As[16][128];
  __shared__ float Ws[16][64];
  const int tid = threadIdx.x;
  const int bm = blockIdx.x, bn = blockIdx.y;
  const int tx = tid & 15, ty = tid >> 4;          // 16 x 16 thread grid
  const int ar = tid >> 1, ac = (tid & 1) << 3;    // A-tile load map (128x16)
  const int wr = tid >> 2, wc = (tid & 3) << 2;    // W-tile load map (64x16)
  int arow = bm*128 + ar;
  int asrc = rowmap ? rowmap[arow] : arow;
  const float* Arow = A + (size_t)asrc * Kd;
  int wrow = bn*64 + wr;
  const float* Wrow = (wrow < Nn) ? (Wt + (size_t)wrow * Kd) : nullptr;
  float acc[8][4];
#pragma unroll
  for (int i = 0; i < 8; ++i)
#pragma unroll
    for (int j = 0; j < 4; ++j) acc[i][j] = 0.f;
  for (int k0 = 0; k0 < Kd; k0 += 16) {
    float4 a0 = *(const float4*)(Arow + k0 + ac);
    float4 a1 = *(const float4*)(Arow + k0 + ac + 4);
    float4 w0 = Wrow ? *(const float4*)(Wrow + k0 + wc) : make_float4(0.f,0.f,0.f,0.f);
    As[ac+0][ar] = a0.x; As[ac+1][ar] = a0.y; As[ac+2][ar] = a0.z; As[ac+3][ar] = a0.w;
    As[ac+4][ar] = a1.x; As[ac+5][ar] = a1.y; As[ac+6][ar] = a1.z; As[ac+7][ar] = a1.w;
    Ws[wc+0][wr] = w0.x; Ws[wc+1][wr] = w0.y; Ws[wc+2][wr] = w0.z; Ws[wc+3][wr] = w0.w;
    __syncthreads();
#pragma unroll
    for (int k = 0; k < 16; ++k) {
      float4 aa0 = *(const float4*)&As[k][ty*8];
      float4 aa1 = *(const float4*)&As[k][ty*8+4];
      float4 bb  = *(const float4*)&Ws[k][tx*4];
      float am[8] = {aa0.x,aa0.y,aa0.z,aa0.w,aa1.x,aa1.y,aa1.z,aa1.w};
      float bv[4] = {bb.x,bb.y,bb.z,bb.w};
#pragma unroll
      for (int i = 0; i < 8; ++i)
#pragma unroll
        for (int j = 0; j < 4; ++j)
          acc[i][j] = fmaf(am[i], bv[j], acc[i][j]);
    }
    __syncthreads();
  }
#pragma unroll
  for (int i = 0; i < 8; ++i) {
    int m = bm*128 + ty*8 + i;   // all M here are multiples of 128
#pragma unroll
    for (int j = 0; j < 4; ++j) {
      int n = bn*64 + tx*4 + j;
      if (n < Nn) {
        float v = acc[i][j];
        if (bias) v += bias[n];
        if (act == 1) v = 0.5f*v*(1.f + erff(v*0.7071067811865475f));
        Y[(size_t)m*Nn + n] = v;
      }
    }
  }
}

// -------------------------- kw softmax + neighbor mixing -------------------
// W[q,d] = q[q,d] * sum_k softmax_k(q·w_k + w_b)[k] * V[q,k,d]
__global__ __launch_bounds__(256) void kwmix_kernel(
    const float* __restrict__ QP, const float* __restrict__ wk,
    const float* __restrict__ wb, const float* __restrict__ V,
    float* __restrict__ W)
{
  const int wave = threadIdx.x >> 6, lane = threadIdx.x & 63;
  const int q = blockIdx.x*4 + wave;
  float qv[4];
#pragma unroll
  for (int j = 0; j < 4; ++j) qv[j] = QP[(size_t)q*256 + lane + 64*j];
  float logit[8];
#pragma unroll
  for (int k = 0; k < 8; ++k) {
    float p = 0.f;
#pragma unroll
    for (int j = 0; j < 4; ++j) p += qv[j]*wk[k*256 + lane + 64*j];
    for (int off = 32; off; off >>= 1) p += __shfl_xor(p, off);
    logit[k] = p + wb[k];
  }
  float mx = logit[0];
#pragma unroll
  for (int k = 1; k < 8; ++k) mx = fmaxf(mx, logit[k]);
  float e[8]; float s = 0.f;
#pragma unroll
  for (int k = 0; k < 8; ++k) { e[k] = expf(logit[k]-mx); s += e[k]; }
  float inv = 1.f/s;
  float acc[4] = {0.f,0.f,0.f,0.f};
#pragma unroll
  for (int k = 0; k < 8; ++k) {
    float kwv = e[k]*inv;
#pragma unroll
    for (int j = 0; j < 4; ++j)
      acc[j] = fmaf(kwv, V[(size_t)(q*8+k)*256 + lane + 64*j], acc[j]);
  }
#pragma unroll
  for (int j = 0; j < 4; ++j)
    W[(size_t)q*256 + lane + 64*j] = qv[j]*acc[j];
}

// -------------------------- LayerNorm over D=256 (1 wave / row) ------------
__global__ __launch_bounds__(256) void ln_kernel(
    const float* __restrict__ a, const float* __restrict__ b,
    float* __restrict__ out, int rows)
{
  const int wave = threadIdx.x >> 6, lane = threadIdx.x & 63;
  const int row = blockIdx.x*4 + wave;
  if (row >= rows) return;
  float v[4];
#pragma unroll
  for (int j = 0; j < 4; ++j) {
    float x = a[(size_t)row*256 + lane + 64*j];
    if (b) x += b[(size_t)row*256 + lane + 64*j];
    v[j] = x;
  }
  float s = v[0]+v[1]+v[2]+v[3];
  for (int off = 32; off; off >>= 1) s += __shfl_xor(s, off);
  float m = s * (1.0f/256.0f);
  float t = 0.f;
#pragma unroll
  for (int j = 0; j < 4; ++j) { float d = v[j]-m; t += d*d; }
  for (int off = 32; off; off >>= 1) t += __shfl_xor(t, off);
  float r = rsqrtf(t * (1.0f/256.0f) + 1e-5f);
#pragma unroll
  for (int j = 0; j < 4; ++j)
    out[(size_t)row*256 + lane + 64*j] = (v[j]-m)*r;
}

// unsort both paths + residual + LN (in-place on X)
__global__ __launch_bounds__(256) void ln_unsort_kernel(
    const float* __restrict__ OUTL, const int* __restrict__ INV,
    float* __restrict__ X)
{
  const int wave = threadIdx.x >> 6, lane = threadIdx.x & 63;
  const int q = blockIdx.x*4 + wave;
  const int i0 = INV[q], i1 = INV[2048 + q];
  float v[4];
#pragma unroll
  for (int j = 0; j < 4; ++j) {
    int d = lane + 64*j;
    v[j] = X[(size_t)q*256 + d]
         + 0.5f*(OUTL[(size_t)i0*256 + d] + OUTL[(size_t)(2048+i1)*256 + d]);
  }
  float s = v[0]+v[1]+v[2]+v[3];
  for (int off = 32; off; off >>= 1) s += __shfl_xor(s, off);
  float m = s * (1.0f/256.0f);
  float t = 0.f;
#pragma unroll
  for (int j = 0; j < 4; ++j) { float d = v[j]-m; t += d*d; }
  for (int off = 32; off; off >>= 1) t += __shfl_xor(t, off);
  float r = rsqrtf(t * (1.0f/256.0f) + 1e-5f);
#pragma unroll
  for (int j = 0; j < 4; ++j)
    X[(size_t)q*256 + lane + 64*j] = (v[j]-m)*r;
}

// -------------------------- causal depthwise conv (KC=4) + SiLU ------------
__global__ void conv_kernel(const float* __restrict__ PROJ,
    const float* __restrict__ Wc, const float* __restrict__ bc,
    float* __restrict__ XBC)
{
  const int c = threadIdx.x;      // 640
  const int bt = blockIdx.x;      // 4096
  const int t = bt & 2047;
  float acc = bc[c];
#pragma unroll
  for (int j = 0; j < 4; ++j) {
    int d = j - 3;
    if (t + d >= 0)
      acc = fmaf(PROJ[(size_t)(bt + d)*1160 + 512 + c], Wc[c*4+j], acc);
  }
  XBC[(size_t)bt*640 + c] = acc / (1.f + expf(-acc));  // silu
}

// -------------------------- dt softplus + dA -------------------------------
// outputs transposed: Ddt/Dda layout [H][B*T] for coalesced scan reads
__global__ void dta_kernel(const float* __restrict__ PROJ,
    const float* __restrict__ dtb, const float* __restrict__ Alog,
    float* __restrict__ Ddt, float* __restrict__ Dda)
{
  const int i = blockIdx.x*256 + threadIdx.x;   // 32768 = 4096*8
  const int bt = i >> 3, hh = i & 7;
  float x = PROJ[(size_t)bt*1160 + 1152 + hh] + dtb[hh];
  float dt = (x > 20.f) ? x : log1pf(expf(x));
  float A = -expf(Alog[hh]);
  Ddt[hh*4096 + bt] = dt;
  Dda[hh*4096 + bt] = expf(dt * A);
}

// -------------------------- scan pass 1: per-chunk S_c, P_c ----------------
// grid = b(2) * h(8) * chunk(32) = 512 blocks, 64 threads (lane = d)
__global__ __launch_bounds__(64) void scan1_kernel(
    const float* __restrict__ XBC, const float* __restrict__ Ddt,
    const float* __restrict__ Dda, float* __restrict__ SCH, float* __restrict__ PC)
{
  const int blk = blockIdx.x;
  const int c = blk & 31, hh = (blk >> 5) & 7, b = blk >> 8;
  const int lane = threadIdx.x;
  const int t0 = (b << 11) + (c << 6);
  __shared__ float Bsh[64][64];
  __shared__ float Xsh[64][64];
  __shared__ float dAs[64], dts[64];
  // float4 tile staging: 16 iters, each wave covers 4 rows coalesced
#pragma unroll
  for (int it = 0; it < 16; ++it) {
    int idx = it*64 + lane;          // 0..1023
    int t = idx >> 4, c4 = (idx & 15) << 2;
    *(float4*)&Bsh[t][c4] = *(const float4*)&XBC[(size_t)(t0 + t)*640 + 512 + c4];
    *(float4*)&Xsh[t][c4] = *(const float4*)&XBC[(size_t)(t0 + t)*640 + (hh<<6) + c4];
  }
  dAs[lane] = Dda[hh*4096 + t0 + lane];
  dts[lane] = Ddt[hh*4096 + t0 + lane];
  __syncthreads();
  float h[64];
#pragma unroll
  for (int s = 0; s < 64; ++s) h[s] = 0.f;
  float p = 1.f;
  for (int t = 0; t < 64; ++t) {
    const float dA = dAs[t];
    const float u = dts[t]*Xsh[t][lane];
    p *= dA;
    const float4* B4 = (const float4*)&Bsh[t][0];
#pragma unroll
    for (int s4 = 0; s4 < 16; ++s4) {
      float4 bv = B4[s4];
      h[4*s4+0] = fmaf(h[4*s4+0], dA, bv.x*u);
      h[4*s4+1] = fmaf(h[4*s4+1], dA, bv.y*u);
      h[4*s4+2] = fmaf(h[4*s4+2], dA, bv.z*u);
      h[4*s4+3] = fmaf(h[4*s4+3], dA, bv.w*u);
    }
  }
  float* op = SCH + (size_t)blk*4096 + lane*64;
#pragma unroll
  for (int s4 = 0; s4 < 16; ++s4)
    ((float4*)op)[s4] = make_float4(h[4*s4], h[4*s4+1], h[4*s4+2], h[4*s4+3]);
  if (lane == 0) PC[blk] = p;
}

// -------------------------- sequential cross-chunk combine (in-place) ------
// After this, SCH[(bh,c)] holds h_start of chunk c.
__global__ void combine_kernel(float* __restrict__ SCH, const float* __restrict__ PC)
{
  const int tid = blockIdx.x*256 + threadIdx.x;   // 65536
  const int bh = tid >> 12, ds = tid & 4095;
  float h = 0.f;
  for (int cc = 0; cc < 32; ++cc) {
    size_t o = ((size_t)(bh*32 + cc) << 12) + ds;
    float s = SCH[o];
    SCH[o] = h;
    h = fmaf(h, PC[bh*32+cc], s);
  }
}

// -------------------------- scan pass 2: exact recurrence + y --------------
__global__ __launch_bounds__(64) void scan2_kernel(
    const float* __restrict__ XBC, const float* __restrict__ Ddt,
    const float* __restrict__ Dda, const float* __restrict__ HST,
    const float* __restrict__ Dm, float* __restrict__ Yout)
{
  const int blk = blockIdx.x;
  const int c = blk & 31, hh = (blk >> 5) & 7, b = blk >> 8;
  const int lane = threadIdx.x;
  const int t0 = (b << 11) + (c << 6);
  __shared__ float Bsh[64][64];
  __shared__ float Csh[64][64];
  __shared__ float Xsh[64][64];
  __shared__ float dAs[64], dts[64];
#pragma unroll
  for (int it = 0; it < 16; ++it) {
    int idx = it*64 + lane;
    int t = idx >> 4, c4 = (idx & 15) << 2;
    *(float4*)&Bsh[t][c4] = *(const float4*)&XBC[(size_t)(t0 + t)*640 + 512 + c4];
    *(float4*)&Csh[t][c4] = *(const float4*)&XBC[(size_t)(t0 + t)*640 + 576 + c4];
    *(float4*)&Xsh[t][c4] = *(const float4*)&XBC[(size_t)(t0 + t)*640 + (hh<<6) + c4];
  }
  dAs[lane] = Dda[hh*4096 + t0 + lane];
  dts[lane] = Ddt[hh*4096 + t0 + lane];
  const float Dh = Dm[hh];
  float h[64];
  const float4* hp = (const float4*)(HST + (size_t)blk*4096 + lane*64);
#pragma unroll
  for (int s4 = 0; s4 < 16; ++s4) {
    float4 t4 = hp[s4];
    h[4*s4+0]=t4.x; h[4*s4+1]=t4.y; h[4*s4+2]=t4.z; h[4*s4+3]=t4.w;
  }
  __syncthreads();
  for (int t = 0; t < 64; ++t) {
    const float dA = dAs[t];
    const float u = dts[t]*Xsh[t][lane];
    float y = 0.f;
    const float4* B4 = (const float4*)&Bsh[t][0];
    const float4* C4 = (const float4*)&Csh[t][0];
#pragma unroll
    for (int s4 = 0; s4 < 16; ++s4) {
      float4 bv = B4[s4];
      float4 cv = C4[s4];
      h[4*s4+0] = fmaf(h[4*s4+0], dA, bv.x*u); y = fmaf(cv.x, h[4*s4+0], y);
      h[4*s4+1] = fmaf(h[4*s4+1], dA, bv.y*u); y = fmaf(cv.y, h[4*s4+1], y);
      h[4*s4+2] = fmaf(h[4*s4+2], dA, bv.z*u); y = fmaf(cv.z, h[4*s4+2], y);
      h[4*s4+3] = fmaf(h[4*s4+3], dA, bv.w*u); y = fmaf(cv.w, h[4*s4+3], y);
    }
    Yout[(size_t)(t0 + t)*512 + (hh<<6) + lane] = y + Dh*Xsh[t][lane];
  }
}

// -------------------------- gate (silu(z)) + RMSNorm over 512 (in-place) ---
__global__ __launch_bounds__(256) void gaterms_kernel(
    float* __restrict__ Y, const float* __restrict__ PROJ,
    const float* __restrict__ rmsw)
{
  const int wave = threadIdx.x >> 6, lane = threadIdx.x & 63;
  const int row = blockIdx.x*4 + wave;   // 4096
  float v[8]; float ss = 0.f;
#pragma unroll
  for (int j = 0; j < 8; ++j) {
    float y = Y[(size_t)row*512 + lane + 64*j];
    float z = PROJ[(size_t)row*1160 + lane + 64*j];
    float g = y * (z / (1.f + expf(-z)));
    v[j] = g; ss += g*g;
  }
  for (int off = 32; off; off >>= 1) ss += __shfl_xor(ss, off);
  float r = rsqrtf(ss * (1.0f/512.0f) + 1e-5f);
#pragma unroll
  for (int j = 0; j < 8; ++j)
    Y[(size_t)row*512 + lane + 64*j] = v[j] * r * rmsw[lane + 64*j];
}

// ---------------------------------------------------------------------------
extern "C" void kernel_launch(void* const* d_in, const int* in_sizes, int n_in,
                              void* d_out, int out_size, void* d_ws, size_t ws_size,
                              hipStream_t stream)
{
  (void)in_sizes; (void)n_in; (void)out_size; (void)ws_size;
  const float* query = (const float*)d_in[0];
  const float* qpos  = (const float*)d_in[1];
  const float* feats = (const float*)d_in[2];
  const float* spos  = (const float*)d_in[3];
  const float* w_q   = (const float*)d_in[4];
  const float* w_v   = (const float*)d_in[5];
  const float* w_o   = (const float*)d_in[6];
  const float* w_k   = (const float*)d_in[7];
  const float* w_b   = (const float*)d_in[8];
  const float* Win   = (const float*)d_in[9];
  const float* Wconv = (const float*)d_in[10];
  const float* bconv = (const float*)d_in[11];
  const float* Alog  = (const float*)d_in[12];
  const float* Dm    = (const float*)d_in[13];
  const float* dtb   = (const float*)d_in[14];
  const float* rmsw  = (const float*)d_in[15];
  const float* Wout  = (const float*)d_in[16];
  const float* fw1   = (const float*)d_in[17];
  const float* fb1   = (const float*)d_in[18];
  const float* fw2   = (const float*)d_in[19];
  const float* fb2   = (const float*)d_in[20];
  const int*   order = (const int*)d_in[21];
  float* out = (float*)d_out;

  char* ws = (char*)d_ws;
  size_t off = 0;
  auto alloc = [&](size_t bytes) -> void* {
    void* p = ws + off;
    off = (off + bytes + 255) & ~(size_t)255;
    return p;
  };
  int*   IDX = (int*)alloc((size_t)2048*8*4);
  int*   INV = (int*)alloc((size_t)4096*4);
  float* PC  = (float*)alloc((size_t)512*4);
  float* Ddt = (float*)alloc((size_t)4096*8*4);
  float* Dda = (float*)alloc((size_t)4096*8*4);
  float* QP  = (float*)alloc((size_t)2048*256*4);
  float* WB  = (float*)alloc((size_t)2048*256*4);
  float* WO  = (float*)alloc((size_t)2048*256*4);
  float* X   = (float*)alloc((size_t)2048*256*4);
  float* XN  = (float*)alloc((size_t)2048*256*4);
  float* U1  = (float*)alloc((size_t)4096*1160*4);  // V (16MB) | PROJ (19MB)
  float* U2  = (float*)alloc((size_t)4096*640*4);   // XBC (10.5MB) | FFH (8.4MB)
  float* SCH = (float*)alloc((size_t)512*4096*4);   // chunk states (in-place h_start)
  float* Yb  = (float*)alloc((size_t)4096*512*4);
  float* U6  = (float*)alloc((size_t)4096*256*4);   // OUTL | FFO
  float* Vb   = U1;  float* PROJ = U1;
  float* XBC  = U2;  float* FFH  = U2;
  float* OUTL = U6;  float* FFO  = U6;

  // --- stage 1: KNN + aggregation ---
  inv_kernel<<<16, 256, 0, stream>>>(order, INV);
  knn_kernel<<<2048, 256, 0, stream>>>(qpos, spos, IDX);
  gemm_kernel<<<dim3(16,4), 256, 0, stream>>>(query, nullptr, w_q, nullptr, QP, 2048,256,256,0);
  gemm_kernel<<<dim3(128,4), 256, 0, stream>>>(feats, IDX, w_v, nullptr, Vb, 16384,256,256,0);
  kwmix_kernel<<<512, 256, 0, stream>>>(QP, w_k, w_b, Vb, WB);
  gemm_kernel<<<dim3(16,4), 256, 0, stream>>>(WB, nullptr, w_o, nullptr, WO, 2048,256,256,0);
  ln_kernel<<<512, 256, 0, stream>>>(WO, query, X, 2048);

  // --- stage 2: two Mamba2 layers ---
  for (int l = 0; l < 2; ++l) {
    ln_kernel<<<512, 256, 0, stream>>>(X, nullptr, XN, 2048);
    gemm_kernel<<<dim3(32,19), 256, 0, stream>>>(XN, order, Win + (size_t)l*1160*256,
                                                 nullptr, PROJ, 4096,1160,256,0);
    conv_kernel<<<4096, 640, 0, stream>>>(PROJ, Wconv + l*640*4, bconv + l*640, XBC);
    dta_kernel<<<128, 256, 0, stream>>>(PROJ, dtb + l*8, Alog + l*8, Ddt, Dda);
    scan1_kernel<<<512, 64, 0, stream>>>(XBC, Ddt, Dda, SCH, PC);
    combine_kernel<<<256, 256, 0, stream>>>(SCH, PC);
    scan2_kernel<<<512, 64, 0, stream>>>(XBC, Ddt, Dda, SCH, Dm + l*8, Yb);
    gaterms_kernel<<<1024, 256, 0, stream>>>(Yb, PROJ, rmsw + l*512);
    gemm_kernel<<<dim3(32,4), 256, 0, stream>>>(Yb, nullptr, Wout + (size_t)l*256*512,
                                                nullptr, OUTL, 4096,256,512,0);
    ln_unsort_kernel<<<512, 256, 0, stream>>>(OUTL, INV, X);
  }

  // --- stage 3: FFN ---
  gemm_kernel<<<dim3(16,16), 256, 0, stream>>>(X, nullptr, fw1, fb1, FFH, 2048,1024,256,1);
  gemm_kernel<<<dim3(16,4), 256, 0, stream>>>(FFH, nullptr, fw2, fb2, FFO, 2048,256,1024,0);
  ln_kernel<<<512, 256, 0, stream>>>(FFO, X, out, 2048);
}